// Round 22
// baseline (106.554 us; speedup 1.0000x reference)
//
#include <hip/hip_runtime.h>
#include <hip/hip_fp16.h>

#define NG 128
#define CHUNK 4096

__device__ __forceinline__ int wave_iscan(int v, int lane) {
#pragma unroll
  for (int off = 1; off < 64; off <<= 1) {
    int u = __shfl_up(v, off, 64);
    if (lane >= off) v += u;
  }
  return v;
}

// ---- bucket totals: int4 dst stream -> LDS hist -> global bucket counts --
__global__ void hist2_kernel(const int* __restrict__ ei, int E, int K,
                             int* __restrict__ gcnt) {
  __shared__ int lh[256];
  int tid = threadIdx.x, blk = blockIdx.x;
  lh[tid] = 0;
  __syncthreads();
  int e0 = blk * CHUNK;
  const int4* d4 = (const int4*)(ei + E + e0);
  for (int i = tid; i < CHUNK / 4; i += 256) {
    int base = e0 + 4 * i;
    if (base + 3 < E) {
      int4 d = d4[i];
      atomicAdd(&lh[d.x >> 8], 1);
      atomicAdd(&lh[d.y >> 8], 1);
      atomicAdd(&lh[d.z >> 8], 1);
      atomicAdd(&lh[d.w >> 8], 1);
    } else {
#pragma unroll
      for (int j = 0; j < 4; ++j) {
        int e = base + j;
        if (e < E) atomicAdd(&lh[ei[E + e] >> 8], 1);
      }
    }
  }
  __syncthreads();
  if (tid < K) {
    int c = lh[tid];
    if (c) atomicAdd(&gcnt[tid], c);
  }
}

// ---- scan K bucket totals (K <= 256) -> bbase, bcur ---------------------
__global__ void scanK_kernel(const int* __restrict__ gcnt, int* __restrict__ bbase,
                             int* __restrict__ bcur, int K) {
  __shared__ int wsum[4];
  int tid = threadIdx.x;  // 256 threads
  int lane = tid & 63, wid = tid >> 6;
  int v = (tid < K) ? gcnt[tid] : 0;
  int inc = wave_iscan(v, lane);
  if (lane == 63) wsum[wid] = inc;
  __syncthreads();
  if (tid == 0) {
    int a = 0;
#pragma unroll
    for (int w = 0; w < 4; ++w) { int t = wsum[w]; wsum[w] = a; a += t; }
  }
  __syncthreads();
  if (tid < K) {
    int exc = inc - v + wsum[wid];
    bbase[tid] = exc;
    bcur[tid] = exc;
  }
}

// ---- partition: LDS hist -> atomic range reservation -> epack runs ------
// epack = (src<<8)|(dst&255); each per-(block,bucket) run written by one CU.
__global__ void part_kernel(const int* __restrict__ ei, int E, int K,
                            int* __restrict__ bcur, unsigned int* __restrict__ epack) {
  __shared__ int lh[256];
  int tid = threadIdx.x, blk = blockIdx.x;
  lh[tid] = 0;
  __syncthreads();
  int e0 = blk * CHUNK;
  const int4* s4 = (const int4*)(ei + e0);
  const int4* d4 = (const int4*)(ei + E + e0);
  // pass 1: local histogram (int4 dst stream)
  for (int i = tid; i < CHUNK / 4; i += 256) {
    int base = e0 + 4 * i;
    if (base + 3 < E) {
      int4 d = d4[i];
      atomicAdd(&lh[d.x >> 8], 1);
      atomicAdd(&lh[d.y >> 8], 1);
      atomicAdd(&lh[d.z >> 8], 1);
      atomicAdd(&lh[d.w >> 8], 1);
    } else {
#pragma unroll
      for (int j = 0; j < 4; ++j) {
        int e = base + j;
        if (e < E) atomicAdd(&lh[ei[E + e] >> 8], 1);
      }
    }
  }
  __syncthreads();
  // pass 2: reserve contiguous ranges; lh becomes the write cursor
  if (tid < K) {
    int c = lh[tid];
    lh[tid] = c ? atomicAdd(&bcur[tid], c) : 0;
  }
  __syncthreads();
  // pass 3: re-read (int4 src+dst) and write epack into reserved runs
  for (int i = tid; i < CHUNK / 4; i += 256) {
    int base = e0 + 4 * i;
    if (base + 3 < E) {
      int4 s = s4[i];
      int4 d = d4[i];
#pragma unroll
      for (int j = 0; j < 4; ++j) {
        unsigned int ss = (unsigned int)((j == 0) ? s.x : (j == 1) ? s.y : (j == 2) ? s.z : s.w);
        unsigned int dd = (unsigned int)((j == 0) ? d.x : (j == 1) ? d.y : (j == 2) ? d.z : d.w);
        int pos = atomicAdd(&lh[dd >> 8], 1);
        epack[pos] = (ss << 8) | (dd & 255u);
      }
    } else {
#pragma unroll
      for (int j = 0; j < 4; ++j) {
        int e = base + j;
        if (e < E) {
          unsigned int ss = (unsigned int)ei[e], dd = (unsigned int)ei[E + e];
          int pos = atomicAdd(&lh[dd >> 8], 1);
          epack[pos] = (ss << 8) | (dd & 255u);
        }
      }
    }
  }
}

// one block per bucket: degree count + scan -> rowptr/deg/dis/xs, esrc fill
__global__ void csr2_kernel(const int* __restrict__ bbase, const int* __restrict__ gcnt,
                            const unsigned int* __restrict__ epack,
                            const float* __restrict__ x, int* __restrict__ deg,
                            int* __restrict__ rowptr, float* __restrict__ dis,
                            float* __restrict__ xs, unsigned short* __restrict__ esrc,
                            int N) {
  __shared__ int lcnt[256];
  __shared__ int lcur[256];
  __shared__ int wsum[4];
  int tid = threadIdx.x, b = blockIdx.x;
  int lane = tid & 63, wid = tid >> 6;
  lcnt[tid] = 0;
  __syncthreads();
  int be0 = bbase[b];
  int be1 = be0 + gcnt[b];
  for (int i = be0 + tid; i < be1; i += 256) atomicAdd(&lcnt[epack[i] & 255u], 1);
  __syncthreads();
  int v = lcnt[tid];
  int inc = wave_iscan(v, lane);
  if (lane == 63) wsum[wid] = inc;
  __syncthreads();
  if (tid == 0) {
    int a = be0;
#pragma unroll
    for (int w = 0; w < 4; ++w) { int t = wsum[w]; wsum[w] = a; a += t; }
  }
  __syncthreads();
  int exc = inc - v + wsum[wid];
  lcur[tid] = exc;
  int node = (b << 8) + tid;
  if (node < N) {
    rowptr[node] = exc;
    deg[node] = v;
    float di = rsqrtf((float)v + 1.0f);  // +1 self loop
    dis[node] = di;
    float4 xv = ((const float4*)x)[node];
    ((float4*)xs)[node] = make_float4(di * xv.x, di * xv.y, di * xv.z, di * xv.w);
  }
  __syncthreads();
  for (int i = be0 + tid; i < be1; i += 256) {
    unsigned int pk = epack[i];
    int pos = atomicAdd(&lcur[pk & 255u], 1);
    esrc[pos] = (unsigned short)(pk >> 8);
  }
}

// ---- layer 1 fused: wave per node; gather xs; h1p = fp16(dis*relu(a@W1+b1))
__global__ void __launch_bounds__(256, 8)
l1_kernel(const int* __restrict__ rowptr, const int* __restrict__ deg,
          const unsigned short* __restrict__ esrc, const float* __restrict__ xs,
          const float* __restrict__ x, const float* __restrict__ dis,
          const float* __restrict__ W1, const float* __restrict__ b1,
          __half* __restrict__ h1p, int N) {
  int tid = threadIdx.x;
  int lane = tid & 63, wid = tid >> 6;
  int d = __builtin_amdgcn_readfirstlane(blockIdx.x * 4 + wid);
  if (d >= N) return;
  float di = dis[d];
  int p = __builtin_amdgcn_readfirstlane(rowptr[d]);
  int n = __builtin_amdgcn_readfirstlane(deg[d]);
  float a0 = 0.f, a1 = 0.f, a2 = 0.f, a3 = 0.f;
  for (int k = lane; k < n; k += 64) {
    int e = esrc[p + k];
    float4 v = ((const float4*)xs)[e];
    a0 += v.x; a1 += v.y; a2 += v.z; a3 += v.w;
  }
  if (lane == 0) {  // self loop: + di*x[d]
    float4 xv = ((const float4*)x)[d];
    a0 = fmaf(di, xv.x, a0); a1 = fmaf(di, xv.y, a1);
    a2 = fmaf(di, xv.z, a2); a3 = fmaf(di, xv.w, a3);
  }
#pragma unroll
  for (int off = 1; off < 64; off <<= 1) {
    a0 += __shfl_xor(a0, off, 64);
    a1 += __shfl_xor(a1, off, 64);
    a2 += __shfl_xor(a2, off, 64);
    a3 += __shfl_xor(a3, off, 64);
  }
  a0 *= di; a1 *= di; a2 *= di; a3 *= di;
  float o = b1[lane] + a0 * W1[lane] + a1 * W1[64 + lane] + a2 * W1[128 + lane] + a3 * W1[192 + lane];
  h1p[(size_t)d * 64 + lane] = __float2half(di * fmaxf(o, 0.0f));
}

// ---- layer 2: grouped row-gather (8 edges/VMEM-round) + matmul + pool ----
__global__ void __launch_bounds__(256, 8)
l2_kernel(const int* __restrict__ rowptr, const int* __restrict__ deg,
          const unsigned short* __restrict__ esrc, const __half* __restrict__ h1p,
          const float* __restrict__ dis, const float* __restrict__ W2,
          const float* __restrict__ b2, const int* __restrict__ batch,
          float* __restrict__ gsum, int N) {
  __shared__ __align__(16) unsigned short ebuf[4][64];
  __shared__ float vbuf[4][64];
  __shared__ float obuf[4][64];
  __shared__ int gbuf[4];
  int tid = threadIdx.x;
  int lane = tid & 63, wid = tid >> 6;
  int g = lane >> 3, c = lane & 7;
  int d0 = blockIdx.x * 4 + wid;
  bool valid = d0 < N;
  int d = __builtin_amdgcn_readfirstlane(valid ? d0 : N - 1);
  float di = dis[d];
  int p = __builtin_amdgcn_readfirstlane(rowptr[d]);
  int n = __builtin_amdgcn_readfirstlane(deg[d]);
  float a0, a1, a2, a3, a4, a5, a6, a7;
  {  // self loop: only group 0 contributes it
    float ms = (g == 0) ? 1.0f : 0.0f;
    uint4 w = *(const uint4*)(h1p + (size_t)d * 64 + 8 * c);
    float2 f0 = __half22float2(*(__half2*)&w.x);
    float2 f1 = __half22float2(*(__half2*)&w.y);
    float2 f2 = __half22float2(*(__half2*)&w.z);
    float2 f3 = __half22float2(*(__half2*)&w.w);
    a0 = ms * f0.x; a1 = ms * f0.y; a2 = ms * f1.x; a3 = ms * f1.y;
    a4 = ms * f2.x; a5 = ms * f2.y; a6 = ms * f3.x; a7 = ms * f3.y;
  }
  for (int base = 0; base < n; base += 64) {
    int m64 = n - base;
    if (m64 > 64) m64 = 64;
    ebuf[wid][lane] = esrc[p + base + ((lane < m64) ? lane : (m64 - 1))];
    for (int k = 0; k < m64; k += 8) {
      int e = ebuf[wid][k + g];              // same-addr broadcast per group
      float m = (k + g < m64) ? 1.0f : 0.0f;
      uint4 w = *(const uint4*)(h1p + (size_t)e * 64 + 8 * c);
      float2 f0 = __half22float2(*(__half2*)&w.x);
      float2 f1 = __half22float2(*(__half2*)&w.y);
      float2 f2 = __half22float2(*(__half2*)&w.z);
      float2 f3 = __half22float2(*(__half2*)&w.w);
      a0 = fmaf(m, f0.x, a0); a1 = fmaf(m, f0.y, a1);
      a2 = fmaf(m, f1.x, a2); a3 = fmaf(m, f1.y, a3);
      a4 = fmaf(m, f2.x, a4); a5 = fmaf(m, f2.y, a5);
      a6 = fmaf(m, f3.x, a6); a7 = fmaf(m, f3.y, a7);
    }
  }
#pragma unroll
  for (int off = 8; off < 64; off <<= 1) {
    a0 += __shfl_xor(a0, off, 64); a1 += __shfl_xor(a1, off, 64);
    a2 += __shfl_xor(a2, off, 64); a3 += __shfl_xor(a3, off, 64);
    a4 += __shfl_xor(a4, off, 64); a5 += __shfl_xor(a5, off, 64);
    a6 += __shfl_xor(a6, off, 64); a7 += __shfl_xor(a7, off, 64);
  }
  if (g == 0) {
    *(float4*)&vbuf[wid][8 * c] = make_float4(di * a0, di * a1, di * a2, di * a3);
    *(float4*)&vbuf[wid][8 * c + 4] = make_float4(di * a4, di * a5, di * a6, di * a7);
  }
  float o = b2[lane];
  const float4* vb4 = (const float4*)vbuf[wid];
#pragma unroll
  for (int kk = 0; kk < 16; ++kk) {
    float4 vv = vb4[kk];
    o = fmaf(vv.x, W2[(kk * 4 + 0) * 64 + lane], o);
    o = fmaf(vv.y, W2[(kk * 4 + 1) * 64 + lane], o);
    o = fmaf(vv.z, W2[(kk * 4 + 2) * 64 + lane], o);
    o = fmaf(vv.w, W2[(kk * 4 + 3) * 64 + lane], o);
  }
  obuf[wid][lane] = fmaxf(o, 0.0f);
  if (lane == 0) gbuf[wid] = valid ? batch[d] : -1;
  __syncthreads();
  if (wid == 0) {
    float s = 0.0f;
    int cur = gbuf[0];
#pragma unroll
    for (int r = 0; r < 4; ++r) {
      int gg = gbuf[r];
      if (gg != cur) {
        if (cur >= 0) atomicAdd(&gsum[cur * 64 + lane], s);
        s = 0.0f;
        cur = gg;
      }
      if (gg >= 0) s += obuf[r][lane];
    }
    if (cur >= 0) atomicAdd(&gsum[cur * 64 + lane], s);
  }
}

// ---- output: mean via binary search on sorted batch ---------------------

__device__ __forceinline__ int lbound(const int* __restrict__ a, int n, int v) {
  int lo = 0, hi = n;
  while (lo < hi) {
    int mid = (lo + hi) >> 1;
    if (a[mid] < v) lo = mid + 1; else hi = mid;
  }
  return lo;
}

__global__ void out_kernel(const float* __restrict__ gsum, const int* __restrict__ batch,
                           int N, float* __restrict__ out) {
  int t = blockIdx.x * blockDim.x + threadIdx.x;
  if (t >= NG * 64) return;
  int g = t >> 6;
  int cnt = lbound(batch, N, g + 1) - lbound(batch, N, g);
  out[t] = gsum[t] / fmaxf((float)cnt, 1.0f);
}

// ---- launch --------------------------------------------------------------

extern "C" void kernel_launch(void* const* d_in, const int* in_sizes, int n_in,
                              void* d_out, int out_size, void* d_ws, size_t ws_size,
                              hipStream_t stream) {
  const float* x = (const float*)d_in[0];
  const int* ei = (const int*)d_in[1];     // [2,E]: src row then dst row
  const int* batch = (const int*)d_in[2];  // sorted graph ids
  const float* W1 = (const float*)d_in[4];
  const float* b1 = (const float*)d_in[5];
  const float* W2 = (const float*)d_in[6];
  const float* b2 = (const float*)d_in[7];

  const int N = in_sizes[0] / 4;           // 50000 (< 65536: ushort esrc ok)
  const int E = in_sizes[1] / 2;
  const int K = (N + 255) >> 8;                 // buckets (dst>>8), <= 256
  const int nblkE = (E + CHUNK - 1) / CHUNK;    // edge chunks

  // ws layout (4B words unless noted):
  // [gsum 8192][gcnt 256] <- zeroed each call
  // [bbase 256][bcur 256][deg N][rowptr N][xs 4N][dis N][h1p 64N halves]
  // [esrc E ushorts][epack E words]
  float* gsum = (float*)d_ws;
  int* gcnt = (int*)(gsum + 64 * NG);
  int* bbase = gcnt + 256;
  int* bcur = bbase + 256;
  int* deg = bcur + 256;
  int* rowptr = deg + N;
  float* xs = (float*)(rowptr + N);             // (8960+2N)%4==0 -> 16B aligned
  float* dis = xs + (size_t)4 * N;
  __half* h1p = (__half*)(dis + N);
  unsigned short* esrc = (unsigned short*)(dis + N + (size_t)32 * N);
  unsigned int* epack = (unsigned int*)(esrc + E);  // E even -> 4B aligned

  hipMemsetAsync(d_ws, 0, (size_t)(64 * NG + 256) * 4, stream);

  const int B = 256;
  hist2_kernel<<<nblkE, 256, 0, stream>>>(ei, E, K, gcnt);
  scanK_kernel<<<1, 256, 0, stream>>>(gcnt, bbase, bcur, K);
  part_kernel<<<nblkE, 256, 0, stream>>>(ei, E, K, bcur, epack);
  csr2_kernel<<<K, 256, 0, stream>>>(bbase, gcnt, epack, x, deg, rowptr, dis, xs, esrc, N);
  l1_kernel<<<(N + 3) / 4, 256, 0, stream>>>(rowptr, deg, esrc, xs, x, dis, W1, b1, h1p, N);
  l2_kernel<<<(N + 3) / 4, 256, 0, stream>>>(rowptr, deg, esrc, h1p, dis, W2, b2, batch, gsum, N);
  out_kernel<<<(NG * 64 + B - 1) / B, B, 0, stream>>>(gsum, batch, N, (float*)d_out);
}